// Round 5
// baseline (2867.264 us; speedup 1.0000x reference)
//
#include <hip/hip_runtime.h>
#include <hip/hip_bf16.h>
#include <cstddef>

#define T_SEQ 512
#define BATCH 256
#define RTOT (BATCH * T_SEQ) /* 131072 rows */

__device__ __forceinline__ float fsigmoid(float x) {
    return 1.0f / (1.0f + __expf(-x));
}
__device__ __forceinline__ float ftanh(float x) {
    // tanh(x) = 1 - 2/(exp(2x)+1); saturates correctly at +-inf
    return 1.0f - 2.0f / (__expf(2.0f * x) + 1.0f);
}

// ---------------------------------------------------------------------------
// Input projection: xp[r, 0:192] = x[r, :] @ W + bi   for both directions.
// One block = 32 rows x 384 cols (f+b). X staged transposed in LDS so the
// inner loop reads 16B-aligned float4 broadcasts (all lanes same addr = free).
// ---------------------------------------------------------------------------
template <int DIN, bool EMBED>
__global__ __launch_bounds__(192) void proj_kernel(
    const float* __restrict__ X, const int* __restrict__ tokens,
    const float* __restrict__ emb,
    const float* __restrict__ Wf, const float* __restrict__ bf_,
    const float* __restrict__ Wb, const float* __restrict__ bb_,
    float* __restrict__ xpf, float* __restrict__ xpb)
{
    constexpr int ROWS = 32;
    constexpr int PAD = 36; // row stride 144B: 16B-aligned float4 reads
    __shared__ __align__(16) float xt[DIN][PAD];
    const int r0 = blockIdx.x * ROWS;
    const int tid = threadIdx.x;

    for (int e = tid; e < ROWS * DIN; e += 192) {
        const int row = e / DIN;
        const int i = e % DIN;
        float v;
        if (EMBED) {
            v = emb[(size_t)tokens[r0 + row] * 64 + i];
        } else {
            v = X[(size_t)(r0 + row) * DIN + i];
        }
        xt[i][row] = v;
    }
    __syncthreads();

    const int col = tid; // 0..191
    #pragma unroll
    for (int d = 0; d < 2; d++) {
        const float* __restrict__ W = d ? Wb : Wf;
        const float* __restrict__ bi = d ? bb_ : bf_;
        float* __restrict__ outp = d ? xpb : xpf;
        float acc[ROWS];
        const float b0 = bi[col];
        #pragma unroll
        for (int r = 0; r < ROWS; r++) acc[r] = b0;
        #pragma unroll 4
        for (int i = 0; i < DIN; i++) {
            const float w = W[i * 192 + col]; // coalesced, L1/L2-hot
            #pragma unroll
            for (int r = 0; r < ROWS; r += 4) {
                const float4 x4 = *(const float4*)&xt[i][r];
                acc[r + 0] = fmaf(x4.x, w, acc[r + 0]);
                acc[r + 1] = fmaf(x4.y, w, acc[r + 1]);
                acc[r + 2] = fmaf(x4.z, w, acc[r + 2]);
                acc[r + 3] = fmaf(x4.w, w, acc[r + 3]);
            }
        }
        #pragma unroll
        for (int r = 0; r < ROWS; r++) {
            outp[(size_t)(r0 + r) * 192 + col] = acc[r];
        }
    }
}

// ---------------------------------------------------------------------------
// Recurrent scan: ONE WAVE (64 lanes) per (batch, direction) chain.
// Lane j owns h[j] and the three weight columns Wh[:, {j, 64+j, 128+j}].
//
// AGPR-RESIDENT WEIGHTS. Rounds 0-4 all failed the same way: the VGPR
// allocator refused to keep 192 weight values live (capped 48-132 VGPRs,
// spilled the rest to L1/L2-backed scratch -> ~2100 stall cyc/step,
// VALUBusy 23%), regardless of launch_bounds / asm pins / waves_per_eu.
// Fix: define each weight via an "=a"-constrained inline asm
// (v_accvgpr_write_b32), making its live range AGPR-class. The 256-entry
// AGPR file has ZERO competing pressure here (no MFMA, arch working set
// ~40), so all 192 values stay resident. Reads are asm VOLATILE
// v_accvgpr_read_b32 (volatile blocks LICM from hoisting 192 reads out of
// the loop, which would recreate the VGPR-pressure problem).
//
// Per step: 64 v_readlane (h broadcast -> SGPR, no LDS, no barrier)
// + 192 v_accvgpr_read + 192 v_fma + ~25 misc ~= 950 cyc issue-bound.
// Gate column order matches jnp.split: [0:64]=z, [64:128]=r, [128:192]=h.
// Masked steps (tok==0) carry state unchanged; y gets the carried state.
// ---------------------------------------------------------------------------
__global__ __launch_bounds__(64)
__attribute__((amdgpu_waves_per_eu(1, 1)))
void gru_scan(
    const float* __restrict__ xpf, const float* __restrict__ xpb,
    const float* __restrict__ whf, const float* __restrict__ whb,
    const float* __restrict__ bbf, const float* __restrict__ bbb,
    const int* __restrict__ tokens,
    float* __restrict__ y,        // [RTOT,128] or nullptr
    float* __restrict__ hfinal)   // [BATCH,128] or nullptr
{
    const int chain = blockIdx.x; // 0..511
    const int b = chain >> 1;
    const int dir = chain & 1;
    const float* __restrict__ xp = dir ? xpb : xpf;
    const float* __restrict__ wh = dir ? whb : whf;
    const float* __restrict__ bb = dir ? bbb : bbf;
    const int j = threadIdx.x; // 0..63 = hidden unit owned by this lane

    // Load weight columns and park them in AGPRs (192 values / lane).
    float wza[64], wra[64], wca[64]; // AGPR-class SSA values after the asm
    #pragma unroll
    for (int i = 0; i < 64; i++) {
        const float v0 = wh[i * 192 + j];        // coalesced per i
        const float v1 = wh[i * 192 + 64 + j];
        const float v2 = wh[i * 192 + 128 + j];
        asm volatile("v_accvgpr_write_b32 %0, %1" : "=a"(wza[i]) : "v"(v0));
        asm volatile("v_accvgpr_write_b32 %0, %1" : "=a"(wra[i]) : "v"(v1));
        asm volatile("v_accvgpr_write_b32 %0, %1" : "=a"(wca[i]) : "v"(v2));
    }
    const float bz = bb[192 + j];        // recurrent bias (bb row 1)
    const float br = bb[192 + 64 + j];
    const float bh = bb[192 + 128 + j];

    const int t0 = dir ? (T_SEQ - 1) : 0;
    const int st = dir ? -1 : 1;
    const size_t base = (size_t)b * T_SEQ;

    // software prefetch pipeline, depth 2
    float xz0, xr0, xh0, xz1, xr1, xh1;
    int tk0, tk1;
    {
        const float* p = xp + (base + t0) * 192 + j;
        xz0 = p[0]; xr0 = p[64]; xh0 = p[128];
        tk0 = tokens[base + t0];
    }
    {
        const float* p = xp + (base + t0 + st) * 192 + j;
        xz1 = p[0]; xr1 = p[64]; xh1 = p[128];
        tk1 = tokens[base + t0 + st];
    }

    float h = 0.0f;

    for (int t = 0; t < T_SEQ; t++) {
        // prefetch t+2
        const int tn = (t + 2 < T_SEQ) ? (t + 2) : (T_SEQ - 1);
        const int te_n = t0 + st * tn;
        const float* pn = xp + (base + te_n) * 192 + j;
        const float xz2 = pn[0], xr2 = pn[64], xh2 = pn[128];
        const int tk2 = tokens[base + te_n];

        // rec_g[j] = sum_i h[i] * Wh[i, g*64+j]; h[i] broadcast via readlane,
        // weights pulled from AGPRs just-in-time (no persistent VGPR pressure)
        float az = bz, ar = br, ah = bh;
        const int hbits = __float_as_int(h);
        #pragma unroll
        for (int i = 0; i < 64; i++) {
            const float hi = __int_as_float(__builtin_amdgcn_readlane(hbits, i));
            float w0, w1, w2;
            asm volatile("v_accvgpr_read_b32 %0, %1" : "=v"(w0) : "a"(wza[i]));
            asm volatile("v_accvgpr_read_b32 %0, %1" : "=v"(w1) : "a"(wra[i]));
            asm volatile("v_accvgpr_read_b32 %0, %1" : "=v"(w2) : "a"(wca[i]));
            az = fmaf(hi, w0, az);
            ar = fmaf(hi, w1, ar);
            ah = fmaf(hi, w2, ah);
        }

        const float z = fsigmoid(xz0 + az);
        const float r = fsigmoid(xr0 + ar);
        const float cand = ftanh(xh0 + r * ah);
        float hnew = z * h + (1.0f - z) * cand;
        if (!(tk0 > 0)) hnew = h;      // Keras mask: carry state
        h = hnew;

        if (y) {
            const int te = t0 + st * t;
            y[(base + te) * 128 + (dir << 6) + j] = h;
        }

        xz0 = xz1; xr0 = xr1; xh0 = xh1; tk0 = tk1;
        xz1 = xz2; xr1 = xr2; xh1 = xh2; tk1 = tk2;
    }
    if (hfinal) {
        hfinal[b * 128 + (dir << 6) + j] = h;
    }
}

// ---------------------------------------------------------------------------
// MLP head: one block (1 wave) per batch row.
// ---------------------------------------------------------------------------
__global__ __launch_bounds__(64) void mlp_kernel(
    const float* __restrict__ hcat, // [BATCH,128]
    const float* __restrict__ wd1, const float* __restrict__ bd1,
    const float* __restrict__ wd2, const float* __restrict__ bd2,
    const float* __restrict__ wd3, const float* __restrict__ bd3,
    const float* __restrict__ wo, const float* __restrict__ bo,
    float* __restrict__ outp)       // [BATCH,28]
{
    const int b = blockIdx.x;
    const int j = threadIdx.x; // 0..63
    __shared__ float x0[128];
    __shared__ float x1[64];
    x0[j] = hcat[b * 128 + j];
    x0[j + 64] = hcat[b * 128 + 64 + j];
    __syncthreads();
    float a = bd1[j];
    #pragma unroll 4
    for (int i = 0; i < 128; i++) a = fmaf(x0[i], wd1[i * 64 + j], a);
    a = fmaxf(a, 0.0f);
    x1[j] = a;
    __syncthreads();
    float a2 = bd2[j];
    #pragma unroll 4
    for (int i = 0; i < 64; i++) a2 = fmaf(x1[i], wd2[i * 64 + j], a2);
    a2 = fmaxf(a2, 0.0f);
    __syncthreads();
    x1[j] = a2;
    __syncthreads();
    float a3 = bd3[j];
    #pragma unroll 4
    for (int i = 0; i < 64; i++) a3 = fmaf(x1[i], wd3[i * 64 + j], a3);
    a3 = fmaxf(a3, 0.0f);
    __syncthreads();
    x1[j] = a3;
    __syncthreads();
    if (j < 28) {
        float o = bo[j];
        #pragma unroll 4
        for (int i = 0; i < 64; i++) o = fmaf(x1[i], wo[i * 28 + j], o);
        outp[b * 28 + j] = fsigmoid(o);
    }
}

// ---------------------------------------------------------------------------
extern "C" void kernel_launch(void* const* d_in, const int* in_sizes, int n_in,
                              void* d_out, int out_size, void* d_ws, size_t ws_size,
                              hipStream_t stream)
{
    const int* tokens  = (const int*)d_in[0];
    const float* emb   = (const float*)d_in[1];
    const float* wi1f  = (const float*)d_in[2];
    const float* wh1f  = (const float*)d_in[3];
    const float* bb1f  = (const float*)d_in[4];
    const float* wi1b  = (const float*)d_in[5];
    const float* wh1b  = (const float*)d_in[6];
    const float* bb1b  = (const float*)d_in[7];
    const float* wi2f  = (const float*)d_in[8];
    const float* wh2f  = (const float*)d_in[9];
    const float* bb2f  = (const float*)d_in[10];
    const float* wi2b  = (const float*)d_in[11];
    const float* wh2b  = (const float*)d_in[12];
    const float* bb2b  = (const float*)d_in[13];
    const float* wi3f  = (const float*)d_in[14];
    const float* wh3f  = (const float*)d_in[15];
    const float* bb3f  = (const float*)d_in[16];
    const float* wi3b  = (const float*)d_in[17];
    const float* wh3b  = (const float*)d_in[18];
    const float* bb3b  = (const float*)d_in[19];
    const float* wd1   = (const float*)d_in[20];
    const float* bd1   = (const float*)d_in[21];
    const float* wd2   = (const float*)d_in[22];
    const float* bd2   = (const float*)d_in[23];
    const float* wd3   = (const float*)d_in[24];
    const float* bd3   = (const float*)d_in[25];
    const float* wo    = (const float*)d_in[26];
    const float* bo    = (const float*)d_in[27];

    // Workspace layout (all fp32) — total EXACTLY 256 MiB:
    //   y    : RTOT*128  (layer output, reused)        67,108,864 B
    //   xpf  : RTOT*192  (fwd input projection)       100,663,296 B
    //   xpb  : RTOT*192  (bwd input projection)       100,663,296 B
    //   hcat : BATCH*128 — ALIASED onto y's space (y is dead after proj3
    //          reads it; the layer-3 scan writes only hfinal).
    float* y    = (float*)d_ws;
    float* xpf  = y + (size_t)RTOT * 128;
    float* xpb  = xpf + (size_t)RTOT * 192;
    float* hcat = y; // alias: y region is dead by the time hcat is written

    const dim3 pb(192), pg(RTOT / 32);

    // Layer 1 (embedding fused into projection)
    proj_kernel<64, true><<<pg, pb, 0, stream>>>(nullptr, tokens, emb,
                                                 wi1f, bb1f, wi1b, bb1b, xpf, xpb);
    gru_scan<<<512, 64, 0, stream>>>(xpf, xpb, wh1f, wh1b, bb1f, bb1b,
                                     tokens, y, nullptr);
    // Layer 2
    proj_kernel<128, false><<<pg, pb, 0, stream>>>(y, nullptr, nullptr,
                                                   wi2f, bb2f, wi2b, bb2b, xpf, xpb);
    gru_scan<<<512, 64, 0, stream>>>(xpf, xpb, wh2f, wh2b, bb2f, bb2b,
                                     tokens, y, nullptr);
    // Layer 3 (final states only)
    proj_kernel<128, false><<<pg, pb, 0, stream>>>(y, nullptr, nullptr,
                                                   wi3f, bb3f, wi3b, bb3b, xpf, xpb);
    gru_scan<<<512, 64, 0, stream>>>(xpf, xpb, wh3f, wh3b, bb3f, bb3b,
                                     tokens, nullptr, hcat);
    // Head
    mlp_kernel<<<256, 64, 0, stream>>>(hcat, wd1, bd1, wd2, bd2, wd3, bd3,
                                       wo, bo, (float*)d_out);
}

// Round 7
// 1704.948 us; speedup vs baseline: 1.6817x; 1.6817x over previous
//
#include <hip/hip_runtime.h>
#include <hip/hip_bf16.h>
#include <cstddef>
#include <cstdint>

#define T_SEQ 512
#define BATCH 256
#define RTOT (BATCH * T_SEQ) /* 131072 rows */
#define CHUNK 32
#define NCHUNK (T_SEQ / CHUNK)

__device__ __forceinline__ float fsigmoid(float x) {
    return 1.0f / (1.0f + __expf(-x));
}
__device__ __forceinline__ float ftanh(float x) {
    // tanh(x) = 1 - 2/(exp(2x)+1); saturates correctly at +-inf
    return 1.0f - 2.0f / (__expf(2.0f * x) + 1.0f);
}

// ---------------------------------------------------------------------------
// Input projection: xp[r, 0:192] = x[r, :] @ W + bi   for both directions.
// (unchanged from round 0 for attribution)
// ---------------------------------------------------------------------------
template <int DIN, bool EMBED>
__global__ __launch_bounds__(192) void proj_kernel(
    const float* __restrict__ X, const int* __restrict__ tokens,
    const float* __restrict__ emb,
    const float* __restrict__ Wf, const float* __restrict__ bf_,
    const float* __restrict__ Wb, const float* __restrict__ bb_,
    float* __restrict__ xpf, float* __restrict__ xpb)
{
    constexpr int ROWS = 32;
    constexpr int PAD = 36; // row stride 144B: 16B-aligned float4 reads
    __shared__ __align__(16) float xt[DIN][PAD];
    const int r0 = blockIdx.x * ROWS;
    const int tid = threadIdx.x;

    for (int e = tid; e < ROWS * DIN; e += 192) {
        const int row = e / DIN;
        const int i = e % DIN;
        float v;
        if (EMBED) {
            v = emb[(size_t)tokens[r0 + row] * 64 + i];
        } else {
            v = X[(size_t)(r0 + row) * DIN + i];
        }
        xt[i][row] = v;
    }
    __syncthreads();

    const int col = tid; // 0..191
    #pragma unroll
    for (int d = 0; d < 2; d++) {
        const float* __restrict__ W = d ? Wb : Wf;
        const float* __restrict__ bi = d ? bb_ : bf_;
        float* __restrict__ outp = d ? xpb : xpf;
        float acc[ROWS];
        const float b0 = bi[col];
        #pragma unroll
        for (int r = 0; r < ROWS; r++) acc[r] = b0;
        #pragma unroll 4
        for (int i = 0; i < DIN; i++) {
            const float w = W[i * 192 + col]; // coalesced, L1/L2-hot
            #pragma unroll
            for (int r = 0; r < ROWS; r += 4) {
                const float4 x4 = *(const float4*)&xt[i][r];
                acc[r + 0] = fmaf(x4.x, w, acc[r + 0]);
                acc[r + 1] = fmaf(x4.y, w, acc[r + 1]);
                acc[r + 2] = fmaf(x4.z, w, acc[r + 2]);
                acc[r + 3] = fmaf(x4.w, w, acc[r + 3]);
            }
        }
        #pragma unroll
        for (int r = 0; r < ROWS; r++) {
            outp[(size_t)(r0 + r) * 192 + col] = acc[r];
        }
    }
}

// ---------------------------------------------------------------------------
// Recurrent scan: 3 waves (192 threads) per (batch,direction) chain; thread k
// owns gate column k (Wh[:,k] in 64 regs/AGPRs).
//
// ROOT-CAUSE FIX under test (r0-r5 post-mortem): __syncthreads() drains
// vmcnt(0) every step, exposing the just-issued xp prefetch's HBM latency
// (~1200 cyc/step across 2 barriers in the r0 kernel; r5's AGPR experiment
// falsified the register-spill theory). Here:
//  * per-step barrier = s_waitcnt lgkmcnt(0) + raw s_barrier + compiler
//    fence. NO vmcnt drain: y-stores stay in flight across steps.
//  * zero per-step global loads: xp is reg-staged per 32-step chunk
//    (8 float4/thread loaded at chunk top for chunk c+1, held ~10k cycles,
//    ds_write'd at chunk bottom -> compiler's vmcnt wait there is free).
//    tokens preloaded to LDS once.
//  * ONE barrier/step: h is per-wave-private (each wave's 64 lanes cover all
//    j, so each wave keeps its own double-buffered h copy; the barrier only
//    publishes the parity-double-buffered gate exchange zr). Safety: writes
//    of parity p at step t+2 can't begin until all waves passed step t+1's
//    barrier, which is after their step-t reads of parity p.
//  * post-barrier asm ::: "memory" fence: __builtin_amdgcn_s_barrier is
//    IntrNoMem in LLVM -- without the fence the compiler may hoist the
//    zr/xbuf ds_reads above the barrier (race).
// Gate order matches jnp.split: [0:64]=z, [64:128]=r, [128:192]=h.
// Masked steps (tok==0) carry state; all waves compute hnew redundantly
// (identical inputs); only wave g==2 writes y/hfinal.
// ---------------------------------------------------------------------------
__global__ __launch_bounds__(192) void gru_scan(
    const float* __restrict__ xpf, const float* __restrict__ xpb,
    const float* __restrict__ whf, const float* __restrict__ whb,
    const float* __restrict__ bbf, const float* __restrict__ bbb,
    const int* __restrict__ tokens,
    float* __restrict__ y,        // [RTOT,128] or nullptr
    float* __restrict__ hfinal)   // [BATCH,128] or nullptr
{
    const int chain = blockIdx.x; // 0..511
    const int b = chain >> 1;
    const int dir = chain & 1;
    const float* __restrict__ xp = dir ? xpb : xpf;
    const float* __restrict__ wh = dir ? whb : whf;
    const float* __restrict__ bbp = dir ? bbb : bbf;
    const int k = threadIdx.x;  // 0..191 = gate column
    const int j = k & 63;
    const int g = k >> 6;       // wave id: 0=z, 1=r, 2=candidate

    __shared__ __align__(16) float xbuf[2][CHUNK][192]; // 49152 B
    __shared__ int   tok_lds[T_SEQ];                    //  2048 B
    __shared__ float zr[2][4][64];                      //  2048 B {z,r,rec_h,x_h}
    __shared__ __align__(16) float hw[3][2][64];        //  1536 B per-wave h

    float whk[64];
    #pragma unroll
    for (int i = 0; i < 64; i++) whk[i] = wh[i * 192 + k];
    const float bhk = bbp[192 + k]; // recurrent bias (bb row 1)

    const size_t base = (size_t)b * T_SEQ;

    // tokens -> LDS once
    for (int i = k; i < T_SEQ; i += 192) tok_lds[i] = tokens[base + i];
    hw[g][0][j] = 0.0f; // own-wave h init, parity 0

    // Reg-staging: one chunk = 32 rows x 192 floats = 1536 float4.
    // 192 threads x 8 float4 each, fully coalesced (16 B/lane).
    float4 stg[8];
    auto load_chunk = [&](int cc) {
        const int row_lo = dir ? (T_SEQ - CHUNK - cc * CHUNK) : (cc * CHUNK);
        const float4* gsrc = (const float4*)(xp + (base + row_lo) * 192);
        #pragma unroll
        for (int s = 0; s < 8; s++) stg[s] = gsrc[s * 192 + k];
    };
    auto write_chunk = [&](int cc) {
        float4* dst = (float4*)&xbuf[cc & 1][0][0];
        #pragma unroll
        for (int s = 0; s < 8; s++) dst[s * 192 + k] = stg[s];
    };

    load_chunk(0);
    write_chunk(0);
    __syncthreads(); // full drain once (staging + tokens + h init)

    const int t0 = dir ? (T_SEQ - 1) : 0;
    const int st = dir ? -1 : 1;
    float hprev = 0.0f;
    float* yp = y ? (y + (base + t0) * 128 + (dir << 6) + j) : nullptr;
    const int ystep = st * 128;
    int te = t0;

    for (int c = 0; c < NCHUNK; c++) {
        const bool more = (c + 1 < NCHUNK);
        if (more) load_chunk(c + 1); // fire now, consumed ~10k cycles later
        const int pb = c & 1;
        #pragma unroll 2
        for (int tl = 0; tl < CHUNK; tl++) {
            const int t = c * CHUNK + tl;
            const int p = t & 1;
            const int tlp = dir ? (CHUNK - 1 - tl) : tl;

            const float xv = xbuf[pb][tlp][k]; // consecutive lanes: conflict-free
            const int tok = tok_lds[te];       // uniform addr: broadcast

            // rec[k] = h . Wh[:,k] + bh[k]; h from OWN wave copy (broadcast)
            float a0 = bhk, a1 = 0.0f, a2 = 0.0f, a3 = 0.0f;
            #pragma unroll
            for (int i = 0; i < 64; i += 4) {
                const float4 h4 = *(const float4*)&hw[g][p][i];
                a0 = fmaf(h4.x, whk[i + 0], a0);
                a1 = fmaf(h4.y, whk[i + 1], a1);
                a2 = fmaf(h4.z, whk[i + 2], a2);
                a3 = fmaf(h4.w, whk[i + 3], a3);
            }
            const float acc = (a0 + a1) + (a2 + a3);

            if (g == 0) {
                zr[p][0][j] = fsigmoid(xv + acc);
            } else if (g == 1) {
                zr[p][1][j] = fsigmoid(xv + acc);
            } else {
                zr[p][2][j] = acc; // rec_h (bias included)
                zr[p][3][j] = xv;  // x_h
            }
            // LDS-only barrier: vmcnt NOT drained (y stores stay in flight)
            asm volatile("s_waitcnt lgkmcnt(0)" ::: "memory");
            __builtin_amdgcn_s_barrier();
            asm volatile("" ::: "memory"); // keep reads below the barrier

            const float zg   = zr[p][0][j];
            const float rg   = zr[p][1][j];
            const float rech = zr[p][2][j];
            const float xh   = zr[p][3][j];
            const float cand = ftanh(xh + rg * rech);
            float hnew = zg * hprev + (1.0f - zg) * cand;
            if (!(tok > 0)) hnew = hprev; // Keras mask: carry state
            hw[g][p ^ 1][j] = hnew;       // own-wave copy only
            if (g == 2 && yp) *yp = hnew; // fire-and-forget global store
            hprev = hnew;
            te += st;
            if (yp) yp += ystep;
        }
        // publish next chunk: ds_write the staged regs (loads issued 32 steps
        // ago -> the compiler's vmcnt wait here is free), then LDS barrier.
        if (more) write_chunk(c + 1);
        asm volatile("s_waitcnt lgkmcnt(0)" ::: "memory");
        __builtin_amdgcn_s_barrier();
        asm volatile("" ::: "memory");
    }
    if (hfinal && g == 2) {
        hfinal[b * 128 + (dir << 6) + j] = hprev;
    }
}

// ---------------------------------------------------------------------------
// MLP head: one block (1 wave) per batch row. (unchanged)
// ---------------------------------------------------------------------------
__global__ __launch_bounds__(64) void mlp_kernel(
    const float* __restrict__ hcat, // [BATCH,128]
    const float* __restrict__ wd1, const float* __restrict__ bd1,
    const float* __restrict__ wd2, const float* __restrict__ bd2,
    const float* __restrict__ wd3, const float* __restrict__ bd3,
    const float* __restrict__ wo, const float* __restrict__ bo,
    float* __restrict__ outp)       // [BATCH,28]
{
    const int b = blockIdx.x;
    const int j = threadIdx.x; // 0..63
    __shared__ float x0[128];
    __shared__ float x1[64];
    x0[j] = hcat[b * 128 + j];
    x0[j + 64] = hcat[b * 128 + 64 + j];
    __syncthreads();
    float a = bd1[j];
    #pragma unroll 4
    for (int i = 0; i < 128; i++) a = fmaf(x0[i], wd1[i * 64 + j], a);
    a = fmaxf(a, 0.0f);
    x1[j] = a;
    __syncthreads();
    float a2 = bd2[j];
    #pragma unroll 4
    for (int i = 0; i < 64; i++) a2 = fmaf(x1[i], wd2[i * 64 + j], a2);
    a2 = fmaxf(a2, 0.0f);
    __syncthreads();
    x1[j] = a2;
    __syncthreads();
    float a3 = bd3[j];
    #pragma unroll 4
    for (int i = 0; i < 64; i++) a3 = fmaf(x1[i], wd3[i * 64 + j], a3);
    a3 = fmaxf(a3, 0.0f);
    __syncthreads();
    x1[j] = a3;
    __syncthreads();
    if (j < 28) {
        float o = bo[j];
        #pragma unroll 4
        for (int i = 0; i < 64; i++) o = fmaf(x1[i], wo[i * 28 + j], o);
        outp[b * 28 + j] = fsigmoid(o);
    }
}

// ---------------------------------------------------------------------------
extern "C" void kernel_launch(void* const* d_in, const int* in_sizes, int n_in,
                              void* d_out, int out_size, void* d_ws, size_t ws_size,
                              hipStream_t stream)
{
    const int* tokens  = (const int*)d_in[0];
    const float* emb   = (const float*)d_in[1];
    const float* wi1f  = (const float*)d_in[2];
    const float* wh1f  = (const float*)d_in[3];
    const float* bb1f  = (const float*)d_in[4];
    const float* wi1b  = (const float*)d_in[5];
    const float* wh1b  = (const float*)d_in[6];
    const float* bb1b  = (const float*)d_in[7];
    const float* wi2f  = (const float*)d_in[8];
    const float* wh2f  = (const float*)d_in[9];
    const float* bb2f  = (const float*)d_in[10];
    const float* wi2b  = (const float*)d_in[11];
    const float* wh2b  = (const float*)d_in[12];
    const float* bb2b  = (const float*)d_in[13];
    const float* wi3f  = (const float*)d_in[14];
    const float* wh3f  = (const float*)d_in[15];
    const float* bb3f  = (const float*)d_in[16];
    const float* wi3b  = (const float*)d_in[17];
    const float* wh3b  = (const float*)d_in[18];
    const float* bb3b  = (const float*)d_in[19];
    const float* wd1   = (const float*)d_in[20];
    const float* bd1   = (const float*)d_in[21];
    const float* wd2   = (const float*)d_in[22];
    const float* bd2   = (const float*)d_in[23];
    const float* wd3   = (const float*)d_in[24];
    const float* bd3   = (const float*)d_in[25];
    const float* wo    = (const float*)d_in[26];
    const float* bo    = (const float*)d_in[27];

    // Workspace layout (all fp32) — total EXACTLY 256 MiB:
    //   y    : RTOT*128  (layer output, reused)        67,108,864 B
    //   xpf  : RTOT*192  (fwd input projection)       100,663,296 B
    //   xpb  : RTOT*192  (bwd input projection)       100,663,296 B
    //   hcat : BATCH*128 — ALIASED onto y's space (y is dead after proj3
    //          reads it; the layer-3 scan writes only hfinal).
    float* y    = (float*)d_ws;
    float* xpf  = y + (size_t)RTOT * 128;
    float* xpb  = xpf + (size_t)RTOT * 192;
    float* hcat = y; // alias: y region is dead by the time hcat is written

    const dim3 pb(192), pg(RTOT / 32);

    // Layer 1 (embedding fused into projection)
    proj_kernel<64, true><<<pg, pb, 0, stream>>>(nullptr, tokens, emb,
                                                 wi1f, bb1f, wi1b, bb1b, xpf, xpb);
    gru_scan<<<512, 192, 0, stream>>>(xpf, xpb, wh1f, wh1b, bb1f, bb1b,
                                      tokens, y, nullptr);
    // Layer 2
    proj_kernel<128, false><<<pg, pb, 0, stream>>>(y, nullptr, nullptr,
                                                   wi2f, bb2f, wi2b, bb2b, xpf, xpb);
    gru_scan<<<512, 192, 0, stream>>>(xpf, xpb, wh2f, wh2b, bb2f, bb2b,
                                      tokens, y, nullptr);
    // Layer 3 (final states only)
    proj_kernel<128, false><<<pg, pb, 0, stream>>>(y, nullptr, nullptr,
                                                   wi3f, bb3f, wi3b, bb3b, xpf, xpb);
    gru_scan<<<512, 192, 0, stream>>>(xpf, xpb, wh3f, wh3b, bb3f, bb3b,
                                      tokens, nullptr, hcat);
    // Head
    mlp_kernel<<<256, 64, 0, stream>>>(hcat, wd1, bd1, wd2, bd2, wd3, bd3,
                                       wo, bo, (float*)d_out);
}